// Round 8
// baseline (175.304 us; speedup 1.0000x reference)
//
#include <hip/hip_runtime.h>
#include <hip/hip_bf16.h>
#include <stdint.h>

// OFPenalty: per-batch Gram (49x49 from 2048x49) -> two 9-step power
// iterations -> penalty scalar. Memory-bound on reading x (102.8 MB; floor
// ~16.3 us at 6.3 TB/s). Timed region also contains harness workspace
// poison fills (~61 us each) we cannot control from here.
//
// R9: barrier-free register Gram. R8 (verified, absmax 0.0) showed the
// fused kernel is NOT BW-bound (60 us @ 10% HBM, warm-cache replay also
// 60 us): the single block's __syncthreads phase-locks all 16 waves, so
// nothing overlaps. This version deletes the staging LDS entirely:
//  - each wave loads its MFMA fragment columns directly from global
//    (lane ln reads x[k+hf*8+j][q*32+ln]: coalesced 128B segments; the
//    2-4x cross-wave re-read is absorbed by L1/L2, HBM unchanged).
//  - no main-loop barriers, no ds ops, no bank conflicts; 16 independent
//    wave schedules + depth-2 register prefetch hide latency.
//  - values/order into cvt+MFMA identical to the verified comp16 path
//    (ascending k-slices per group); A-accumulate ((q0+q1)+q2)+q3 and
//    wave-0 in-register eigen are R8-verified verbatim.
//  - column clamp min(col,48) redirects garbage lanes (masked at A-write)
//    and keeps batch 255 in-bounds (max idx = 25,690,111 = last float).
//  - VGPR: ~112 target; __launch_bounds__(1024) enforces the 128 cap.

#define BATCH 256
#define CDIM  2048
#define NDIM  49
#define GROUPS 4
#define GK     (CDIM / GROUPS)       // 512 k-rows per group
#define NSLICE (GK / 16)             // 32 k-slices of 16 per group
#define SLICE_FLOATS (16 * NDIM)     // 784

typedef __bf16 bf16x8 __attribute__((ext_vector_type(8)));
typedef float  f32x16 __attribute__((ext_vector_type(16)));

__global__ __launch_bounds__(1024) void fused_kernel(
    const float* __restrict__ x, const float* __restrict__ x0,
    float* __restrict__ pen) {
  __shared__ __align__(16) float A[NDIM * NDIM + 3];  // 9.6 KB (only LDS)

  const int tid  = threadIdx.x;       // 0..1023
  const int b    = blockIdx.x;        // batch 0..255
  const int g    = tid >> 8;          // K-group 0..3
  const int lane = tid & 63;
  const int gw   = (tid >> 6) & 3;    // wave within group -> quadrant
  const int l5   = lane & 31;
  const int hf   = lane >> 5;         // k-half selector
  const int qm = gw >> 1, qn = gw & 1;
  const int m = qm * 32 + l5;         // output row this lane feeds
  const int n = qn * 32 + l5;         // output col this lane feeds
  const int ca = (m < NDIM) ? m : (NDIM - 1);  // clamped load columns
  const int cb = (n < NDIM) ? n : (NDIM - 1);
  const int offA = hf * (8 * NDIM) + ca;
  const int offB = hf * (8 * NDIM) + cb;
  const bool same = (qm == qn);       // wave-uniform: A/B operands equal

  const float* gbase = x + (size_t)b * (CDIM * NDIM)
                         + (size_t)g * (GK * NDIM);

  f32x16 c1, c2, c3;
#pragma unroll
  for (int i = 0; i < 16; ++i) { c1[i] = 0.f; c2[i] = 0.f; c3[i] = 0.f; }

  float a0[8], b0[8], a1[8], b1[8];

  auto LOAD = [&](int s, float (&a)[8], float (&bb)[8]) {
    const float* p = gbase + s * SLICE_FLOATS;
#pragma unroll
    for (int j = 0; j < 8; ++j) a[j] = p[j * NDIM + offA];
    if (!same) {
#pragma unroll
      for (int j = 0; j < 8; ++j) bb[j] = p[j * NDIM + offB];
    }
  };
  auto CVT = [&](const float (&r)[8], bf16x8& hi, bf16x8& lo) {
#pragma unroll
    for (int j = 0; j < 8; ++j) {
      float e = r[j];
      __bf16 h = (__bf16)e;            // RNE high part
      hi[j] = h;
      lo[j] = (__bf16)(e - (float)h);  // exact residual, then RNE
    }
  };
  auto COMPUTE = [&](const float (&a)[8], const float (&bb)[8]) {
    bf16x8 ah, al, bh, bl;
    CVT(a, ah, al);
    if (same) { bh = ah; bl = al; }
    else      CVT(bb, bh, bl);
    c1 = __builtin_amdgcn_mfma_f32_32x32x16_bf16(ah, bh, c1, 0, 0, 0);
    c2 = __builtin_amdgcn_mfma_f32_32x32x16_bf16(ah, bl, c2, 0, 0, 0);
    c3 = __builtin_amdgcn_mfma_f32_32x32x16_bf16(al, bh, c3, 0, 0, 0);
  };

  // depth-2 register prefetch, ascending k-slices (verified order)
  LOAD(0, a0, b0);
  for (int s = 0; s < NSLICE; s += 2) {
    LOAD(s + 1, a1, b1);
    COMPUTE(a0, b0);
    if (s + 2 < NSLICE) LOAD(s + 2, a0, b0);
    COMPUTE(a1, b1);
  }

  // Accumulate groups into A in ascending-k order: bit-identical to the
  // verified quarter-sum ((q0+q1)+q2)+q3.
  // C/D layout (m74/m101): col = lane&31, row = (reg&3)+8*(reg>>2)+4*(lane>>5)
  __syncthreads();
#pragma unroll
  for (int gg = 0; gg < GROUPS; ++gg) {
    if (g == gg) {
#pragma unroll
      for (int r = 0; r < 16; ++r) {
        int row = (r & 3) + 8 * (r >> 2) + 4 * hf;
        int mm = qm * 32 + row;
        if (mm < NDIM && n < NDIM) {
          float v = c1[r] + c2[r] + c3[r];
          if (gg == 0) A[mm * NDIM + n] = v;
          else         A[mm * NDIM + n] += v;
        }
      }
    }
    __syncthreads();
  }

  // ---- power iteration: wave 0 only, fully in-register (R5/R8-verified) ----
  if (tid < 64) {
    const bool act = (tid < NDIM);
    float Ar[NDIM];
    {
      const float* Arow = &A[(act ? tid : (NDIM - 1)) * NDIM];
#pragma unroll
      for (int k = 0; k < NDIM; ++k) Ar[k] = Arow[k];
    }
    float xl = act ? x0[b * NDIM + tid] : 0.f;

    // 9x {x = normalize((A - sI) x)}, then Rayleigh num/den on one more
    // matvec. xl stays as final x (warm start for 2nd call).
    auto rayleigh = [&](float shift) -> float {
      for (int it = 0; it < 9; ++it) {
        float a0r = 0.f, a1r = 0.f, a2r = 0.f, a3r = 0.f;
#pragma unroll
        for (int k = 0; k < 48; k += 4) {
          a0r = fmaf(Ar[k + 0], __shfl(xl, k + 0, 64), a0r);
          a1r = fmaf(Ar[k + 1], __shfl(xl, k + 1, 64), a1r);
          a2r = fmaf(Ar[k + 2], __shfl(xl, k + 2, 64), a2r);
          a3r = fmaf(Ar[k + 3], __shfl(xl, k + 3, 64), a3r);
        }
        a0r = fmaf(Ar[48], __shfl(xl, 48, 64), a0r);
        float y = act ? (((a0r + a1r) + (a2r + a3r)) - shift * xl) : 0.f;
        float s2 = y * y;
#pragma unroll
        for (int o = 32; o; o >>= 1) s2 += __shfl_xor(s2, o, 64);
        xl = y / fmaxf(sqrtf(s2), 1e-12f);  // F.normalize eps
      }
      float a0r = 0.f, a1r = 0.f, a2r = 0.f, a3r = 0.f;
#pragma unroll
      for (int k = 0; k < 48; k += 4) {
        a0r = fmaf(Ar[k + 0], __shfl(xl, k + 0, 64), a0r);
        a1r = fmaf(Ar[k + 1], __shfl(xl, k + 1, 64), a1r);
        a2r = fmaf(Ar[k + 2], __shfl(xl, k + 2, 64), a2r);
        a3r = fmaf(Ar[k + 3], __shfl(xl, k + 3, 64), a3r);
      }
      a0r = fmaf(Ar[48], __shfl(xl, 48, 64), a0r);
      float yy = act ? (((a0r + a1r) + (a2r + a3r)) - shift * xl) : 0.f;
      float num = yy * xl;
      float den = xl * xl;
#pragma unroll
      for (int o = 32; o; o >>= 1) {
        num += __shfl_xor(num, o, 64);
        den += __shfl_xor(den, o, 64);
      }
      return num / den;
    };

    float largest  = rayleigh(0.f);
    float smallest = rayleigh(largest) + largest;  // warm start: xl == x1
    if (tid == 0) {
      float r = largest / smallest - 1.f;
      pen[b] = r * r;
    }
  }
}

__global__ __launch_bounds__(64) void finish_kernel(
    const float* __restrict__ pen, float* __restrict__ out) {
  const int t = threadIdx.x;
  float s = pen[t] + pen[t + 64] + pen[t + 128] + pen[t + 192];
#pragma unroll
  for (int o = 32; o; o >>= 1) s += __shfl_xor(s, o, 64);
  if (t == 0) out[0] = s * (1.0f / (float)BATCH);  // BETA = 1
}

extern "C" void kernel_launch(void* const* d_in, const int* in_sizes, int n_in,
                              void* d_out, int out_size, void* d_ws,
                              size_t ws_size, hipStream_t stream) {
  const float* x  = (const float*)d_in[0];   // [256,2048,7,7] fp32
  const float* x0 = (const float*)d_in[1];   // [256,49,1] fp32 (pre-normalized)
  float* out = (float*)d_out;                // scalar fp32
  float* pen = (float*)d_ws;                 // 256 fp32 per-batch penalties

  fused_kernel<<<BATCH, 1024, 0, stream>>>(x, x0, pen);
  finish_kernel<<<1, 64, 0, stream>>>(pen, out);
}

// Round 9
// 165.255 us; speedup vs baseline: 1.0608x; 1.0608x over previous
//
#include <hip/hip_runtime.h>
#include <hip/hip_bf16.h>
#include <stdint.h>

// OFPenalty: per-batch Gram (49x49 from 2048x49) -> two 9-step power
// iterations -> penalty scalar. x-read floor ~16.3 us; timed region also
// has a ~60 us workspace poison fill + ~45 us of tiny harness dispatches.
//
// R10: register-pressure fix. R8/R9 both reported VGPR_Count=64 and ran
// 60-70 us EVEN WITH WARM CACHES (R9 replay: FETCH 8 KB, same 68 us) ->
// loads serialized at MLP~1. Cause: __launch_bounds__(1024) caps the
// unified reg file at ~128/wave; 48 AGPRs of accumulators squeeze staging
// arrays into AGPRs, and global_load can't target AGPR -> per-load drain.
// Fix: 512 threads (2 waves/SIMD -> ~256 regs/wave), 2 K-groups x 4 waves,
// each group = R3's verified pipeline verbatim on its K-half (CHUNK=64,
// 16 chunks, same staging indices, same comp16). Staging stays in VGPRs,
// 16-load batches stay in flight. Eigen/A-accumulate verified (R5/R8).

#define BATCH 256
#define CDIM  2048
#define NDIM  49
#define GROUPS 2
#define GK    (CDIM / GROUPS)        // 1024 k-rows per group
#define CHUNK 64                     // k rows per LDS stage
#define NCHUNK (GK / CHUNK)          // 16 chunks per group
#define ITEMS (NDIM * (CHUNK / 8))   // 392 16B k-blocks per chunk
#define CHUNK_FLOATS (CHUNK * NDIM)  // 3136

typedef __bf16 bf16x8 __attribute__((ext_vector_type(8)));
typedef float  f32x16 __attribute__((ext_vector_type(16)));
typedef float  f32x4  __attribute__((ext_vector_type(4)));

union V16 {
  f32x4  f4;
  bf16x8 b8;
};

__device__ __forceinline__ void load8(const float* __restrict__ g,
                                      float (&r)[8]) {
#pragma unroll
  for (int j = 0; j < 8; ++j) r[j] = g[j * NDIM];
}

__device__ __forceinline__ void cvt_store(const float (&r)[8], float* Hb,
                                          float* Lb, int w) {
  bf16x8 hv, lv;
#pragma unroll
  for (int j = 0; j < 8; ++j) {
    float e = r[j];
    __bf16 h = (__bf16)e;            // RNE high part
    hv[j] = h;
    lv[j] = (__bf16)(e - (float)h);  // exact residual, then RNE
  }
  V16 a, b;
  a.b8 = hv;
  b.b8 = lv;
  *(f32x4*)(Hb + w) = a.f4;   // ds_write_b128, swizzled slot
  *(f32x4*)(Lb + w) = b.f4;
}

__device__ __forceinline__ void comp16(const float* Hb, const float* Lb,
                                       int m, int n, int hf, f32x16& c1,
                                       f32x16& c2, f32x16& c3) {
  const f32x4* H = (const f32x4*)Hb;
  const f32x4* L = (const f32x4*)Lb;
#pragma unroll
  for (int s = 0; s < 4; ++s) {
    const int blk = 2 * s + hf;   // k-halves: kk = s*16 + hf*8
    V16 ah, al, bh, bl;
    ah.f4 = H[m * 8 + (blk ^ (m & 7))];
    al.f4 = L[m * 8 + (blk ^ (m & 7))];
    bh.f4 = H[n * 8 + (blk ^ (n & 7))];
    bl.f4 = L[n * 8 + (blk ^ (n & 7))];
    c1 = __builtin_amdgcn_mfma_f32_32x32x16_bf16(ah.b8, bh.b8, c1, 0, 0, 0);
    c2 = __builtin_amdgcn_mfma_f32_32x32x16_bf16(ah.b8, bl.b8, c2, 0, 0, 0);
    c3 = __builtin_amdgcn_mfma_f32_32x32x16_bf16(al.b8, bh.b8, c3, 0, 0, 0);
  }
}

__global__ __launch_bounds__(512) void fused_kernel(
    const float* __restrict__ x, const float* __restrict__ x0,
    float* __restrict__ pen) {
  // Per group g: Hi0 = lds + g*8192, Lo0 = +2048, Hi1 = +4096, Lo1 = +6144
  // (float units). Buffer layout identical to R3: row n (0..48; 49-63
  // stale, masked at A-write), 8 16B k-blocks, XOR-swizzled by (n&7).
  __shared__ __align__(16) float lds[GROUPS * 8192];   // 64 KB
  __shared__ __align__(16) float A[NDIM * NDIM + 3];   // 9.6 KB

  const int tid  = threadIdx.x;       // 0..511
  const int b    = blockIdx.x;        // batch 0..255
  const int g    = tid >> 8;          // K-group 0..1
  const int ltid = tid & 255;         // thread within group (== R3 tid)
  const int lane = tid & 63;
  const int gw   = (tid >> 6) & 3;    // wave within group -> quadrant
  const int ln   = lane & 31;
  const int hf   = lane >> 5;         // k-half selector
  const int qm = gw >> 1, qn = gw & 1;
  const int m = qm * 32 + ln;         // A row this lane feeds
  const int n = qn * 32 + ln;         // B col this lane feeds

  float* const buf0 = lds + g * 8192;          // Hi0 (Lo0 = +2048)
  float* const buf1 = lds + g * 8192 + 4096;   // Hi1 (Lo1 = +2048)

  const float* gbase = x + (size_t)b * (CDIM * NDIM)
                         + (size_t)g * (GK * NDIM);

  // staging item assignment (constant across chunks): item = kq*49 + n_s
  const int i0 = ltid;                      // always < 392
  const int i1 = ltid + 256;
  const bool v1 = (i1 < ITEMS);             // ltid < 136
  const int kq0 = (i0 * 1338) >> 16;        // exact /49 for i < 2520
  const int n0  = i0 - 49 * kq0;
  const int kq1 = (i1 * 1338) >> 16;
  const int n1  = i1 - 49 * kq1;
  const int g0  = kq0 * (8 * NDIM) + n0;    // float offset of (k=8*kq, n)
  const int g1  = kq1 * (8 * NDIM) + n1;
  const int w0  = n0 * 32 + 4 * (kq0 ^ (n0 & 7));  // slot (swizzled)
  const int w1  = n1 * 32 + 4 * (kq1 ^ (n1 & 7));

  f32x16 c1, c2, c3;
#pragma unroll
  for (int i = 0; i < 16; ++i) { c1[i] = 0.f; c2[i] = 0.f; c3[i] = 0.f; }

  float sA0[8], sA1[8], sB0[8], sB1[8];

  // prologue: chunk 0 -> regs
  load8(gbase + g0, sA0);
  if (v1) load8(gbase + g1, sA1);

  for (int ch = 0; ch < NCHUNK; ch += 2) {
    {  // prefetch chunk ch+1 (stays in flight across store+barrier)
      const float* gch = gbase + (size_t)(ch + 1) * CHUNK_FLOATS;
      load8(gch + g0, sB0);
      if (v1) load8(gch + g1, sB1);
    }
    cvt_store(sA0, buf0, buf0 + 2048, w0);
    if (v1) cvt_store(sA1, buf0, buf0 + 2048, w1);
    __syncthreads();  // buf0 ready; everyone done reading buf1 (prev iter)
    comp16(buf0, buf0 + 2048, m, n, hf, c1, c2, c3);

    if (ch + 2 < NCHUNK) {
      const float* gch = gbase + (size_t)(ch + 2) * CHUNK_FLOATS;
      load8(gch + g0, sA0);
      if (v1) load8(gch + g1, sA1);
    }
    cvt_store(sB0, buf1, buf1 + 2048, w0);
    if (v1) cvt_store(sB1, buf1, buf1 + 2048, w1);
    __syncthreads();  // buf1 ready; everyone done reading buf0
    comp16(buf1, buf1 + 2048, m, n, hf, c1, c2, c3);
  }

  // Accumulate groups into A: g0 (k<1024) writes, g1 adds.
  // C/D layout (m74/m101): col = lane&31, row = (reg&3)+8*(reg>>2)+4*(lane>>5)
  __syncthreads();
#pragma unroll
  for (int gg = 0; gg < GROUPS; ++gg) {
    if (g == gg) {
#pragma unroll
      for (int r = 0; r < 16; ++r) {
        int row = (r & 3) + 8 * (r >> 2) + 4 * hf;
        int mm = qm * 32 + row;
        if (mm < NDIM && n < NDIM) {
          float v = c1[r] + c2[r] + c3[r];
          if (gg == 0) A[mm * NDIM + n] = v;
          else         A[mm * NDIM + n] += v;
        }
      }
    }
    __syncthreads();
  }

  // ---- power iteration: wave 0 only, fully in-register (R5/R8-verified) ----
  if (tid < 64) {
    const bool act = (tid < NDIM);
    float Ar[NDIM];
    {
      const float* Arow = &A[(act ? tid : (NDIM - 1)) * NDIM];
#pragma unroll
      for (int k = 0; k < NDIM; ++k) Ar[k] = Arow[k];
    }
    float xl = act ? x0[b * NDIM + tid] : 0.f;

    // 9x {x = normalize((A - sI) x)}, then Rayleigh num/den on one more
    // matvec. xl stays as final x (warm start for 2nd call).
    auto rayleigh = [&](float shift) -> float {
      for (int it = 0; it < 9; ++it) {
        float a0r = 0.f, a1r = 0.f, a2r = 0.f, a3r = 0.f;
#pragma unroll
        for (int k = 0; k < 48; k += 4) {
          a0r = fmaf(Ar[k + 0], __shfl(xl, k + 0, 64), a0r);
          a1r = fmaf(Ar[k + 1], __shfl(xl, k + 1, 64), a1r);
          a2r = fmaf(Ar[k + 2], __shfl(xl, k + 2, 64), a2r);
          a3r = fmaf(Ar[k + 3], __shfl(xl, k + 3, 64), a3r);
        }
        a0r = fmaf(Ar[48], __shfl(xl, 48, 64), a0r);
        float y = act ? (((a0r + a1r) + (a2r + a3r)) - shift * xl) : 0.f;
        float s2 = y * y;
#pragma unroll
        for (int o = 32; o; o >>= 1) s2 += __shfl_xor(s2, o, 64);
        xl = y / fmaxf(sqrtf(s2), 1e-12f);  // F.normalize eps
      }
      float a0r = 0.f, a1r = 0.f, a2r = 0.f, a3r = 0.f;
#pragma unroll
      for (int k = 0; k < 48; k += 4) {
        a0r = fmaf(Ar[k + 0], __shfl(xl, k + 0, 64), a0r);
        a1r = fmaf(Ar[k + 1], __shfl(xl, k + 1, 64), a1r);
        a2r = fmaf(Ar[k + 2], __shfl(xl, k + 2, 64), a2r);
        a3r = fmaf(Ar[k + 3], __shfl(xl, k + 3, 64), a3r);
      }
      a0r = fmaf(Ar[48], __shfl(xl, 48, 64), a0r);
      float yy = act ? (((a0r + a1r) + (a2r + a3r)) - shift * xl) : 0.f;
      float num = yy * xl;
      float den = xl * xl;
#pragma unroll
      for (int o = 32; o; o >>= 1) {
        num += __shfl_xor(num, o, 64);
        den += __shfl_xor(den, o, 64);
      }
      return num / den;
    };

    float largest  = rayleigh(0.f);
    float smallest = rayleigh(largest) + largest;  // warm start: xl == x1
    if (tid == 0) {
      float r = largest / smallest - 1.f;
      pen[b] = r * r;
    }
  }
}

__global__ __launch_bounds__(64) void finish_kernel(
    const float* __restrict__ pen, float* __restrict__ out) {
  const int t = threadIdx.x;
  float s = pen[t] + pen[t + 64] + pen[t + 128] + pen[t + 192];
#pragma unroll
  for (int o = 32; o; o >>= 1) s += __shfl_xor(s, o, 64);
  if (t == 0) out[0] = s * (1.0f / (float)BATCH);  // BETA = 1
}

extern "C" void kernel_launch(void* const* d_in, const int* in_sizes, int n_in,
                              void* d_out, int out_size, void* d_ws,
                              size_t ws_size, hipStream_t stream) {
  const float* x  = (const float*)d_in[0];   // [256,2048,7,7] fp32
  const float* x0 = (const float*)d_in[1];   // [256,49,1] fp32 (pre-normalized)
  float* out = (float*)d_out;                // scalar fp32
  float* pen = (float*)d_ws;                 // 256 fp32 per-batch penalties

  fused_kernel<<<BATCH, 512, 0, stream>>>(x, x0, pen);
  finish_kernel<<<1, 64, 0, stream>>>(pen, out);
}